// Round 1
// baseline (25.998 us; speedup 1.0000x reference)
//
#include <hip/hip_runtime.h>

// Problem constants (match reference setup_inputs)
#define B 256
#define L 512
#define H 256      // hid dim; 64 lanes * float4 = 256 exactly
#define K 512
#define CHUNKS 4           // blocks per batch sample
#define KPB (K / CHUNKS)   // 128 outputs per block
#define THREADS 256        // 4 waves; each wave does KPB/4 = 32 outputs

__global__ __launch_bounds__(THREADS)
void preds_fused_kernel(const int* __restrict__ entities,
                        const int* __restrict__ actions,
                        const int* __restrict__ action_keys,
                        const float* __restrict__ encoded,
                        const float* __restrict__ rel_emb,
                        float* __restrict__ out)
{
    const int blk   = blockIdx.x;
    const int b     = blk >> 2;      // CHUNKS == 4
    const int chunk = blk & 3;
    const int t     = threadIdx.x;
    const int lane  = t & 63;
    const int wave  = t >> 6;

    __shared__ int s_count;
    if (t == 0) s_count = 0;
    __syncthreads();

    // ---- last non-pad index: count = sum(entities[b,:] != 0) ----
    int c = (entities[b * L + t] != 0) + (entities[b * L + t + 256] != 0);
    #pragma unroll
    for (int off = 32; off > 0; off >>= 1)
        c += __shfl_down(c, off, 64);
    if (lane == 0) atomicAdd(&s_count, c);
    __syncthreads();

    int idx = s_count - 1;
    idx = max(0, min(L - 1, idx));   // matches JAX clip-mode gather

    // ---- enc_last fragment: lane holds 4 consecutive floats ----
    const float4 e =
        *(const float4*)&encoded[((size_t)(b * L + idx)) * H + lane * 4];

    // ---- gather + dot over this wave's 32 outputs ----
    const int  kbase = chunk * KPB + wave * (KPB / 4);
    const int* ak    = action_keys + b * K;

    #pragma unroll 2
    for (int i = 0; i < KPB / 4; i += 4) {
        const int k0 = kbase + i;
        // broadcast loads (all lanes same addr -> single cacheline each)
        int a0 = actions[ak[k0 + 0]];
        int a1 = actions[ak[k0 + 1]];
        int a2 = actions[ak[k0 + 2]];
        int a3 = actions[ak[k0 + 3]];

        float4 r0 = *(const float4*)&rel_emb[(size_t)a0 * H + lane * 4];
        float4 r1 = *(const float4*)&rel_emb[(size_t)a1 * H + lane * 4];
        float4 r2 = *(const float4*)&rel_emb[(size_t)a2 * H + lane * 4];
        float4 r3 = *(const float4*)&rel_emb[(size_t)a3 * H + lane * 4];

        float p0 = r0.x * e.x + r0.y * e.y + r0.z * e.z + r0.w * e.w;
        float p1 = r1.x * e.x + r1.y * e.y + r1.z * e.z + r1.w * e.w;
        float p2 = r2.x * e.x + r2.y * e.y + r2.z * e.z + r2.w * e.w;
        float p3 = r3.x * e.x + r3.y * e.y + r3.z * e.z + r3.w * e.w;

        #pragma unroll
        for (int off = 1; off < 64; off <<= 1) {
            p0 += __shfl_xor(p0, off, 64);
            p1 += __shfl_xor(p1, off, 64);
            p2 += __shfl_xor(p2, off, 64);
            p3 += __shfl_xor(p3, off, 64);
        }
        if (lane == 0) {
            out[b * K + k0 + 0] = p0;
            out[b * K + k0 + 1] = p1;
            out[b * K + k0 + 2] = p2;
            out[b * K + k0 + 3] = p3;
        }
    }
}

extern "C" void kernel_launch(void* const* d_in, const int* in_sizes, int n_in,
                              void* d_out, int out_size, void* d_ws, size_t ws_size,
                              hipStream_t stream)
{
    const int*   entities    = (const int*)d_in[0];
    // d_in[1] = relations (unused by the reference computation)
    const int*   actions     = (const int*)d_in[2];
    const int*   action_keys = (const int*)d_in[3];
    const float* encoded     = (const float*)d_in[4];
    const float* rel_emb     = (const float*)d_in[5];
    float*       out         = (float*)d_out;

    hipLaunchKernelGGL(preds_fused_kernel,
                       dim3(B * CHUNKS), dim3(THREADS), 0, stream,
                       entities, actions, action_keys, encoded, rel_emb, out);
}

// Round 2
// 25.048 us; speedup vs baseline: 1.0379x; 1.0379x over previous
//
#include <hip/hip_runtime.h>

// Problem constants (match reference setup_inputs)
#define B 256
#define L 512
#define H 256
#define K 512
#define CHUNKS 8            // blocks per batch sample
#define KPB (K / CHUNKS)    // 64 outputs per block
#define THREADS 256         // 4 waves
#define KPW (KPB / 4)       // 16 outputs per wave
#define KPG (KPW / 4)       // 4 outputs per 16-lane group

__global__ __launch_bounds__(THREADS)
void preds_fused_kernel(const int* __restrict__ entities,
                        const int* __restrict__ actions,
                        const int* __restrict__ action_keys,
                        const float* __restrict__ encoded,
                        const float* __restrict__ rel_emb,
                        float* __restrict__ out)
{
    const int blk   = blockIdx.x;
    const int b     = blk >> 3;      // CHUNKS == 8
    const int chunk = blk & 7;
    const int t     = threadIdx.x;
    const int lane  = t & 63;
    const int wave  = t >> 6;
    const int gid   = lane >> 4;     // 16-lane group id (0..3)
    const int gl    = lane & 15;     // lane within group

    __shared__ int s_count;
    if (t == 0) s_count = 0;
    __syncthreads();

    // ---- last non-pad index: count = sum(entities[b,:] != 0) ----
    {
        unsigned long long m0 = __ballot(entities[b * L + t] != 0);
        unsigned long long m1 = __ballot(entities[b * L + t + 256] != 0);
        if (lane == 0) atomicAdd(&s_count, __popcll(m0) + __popcll(m1));
    }
    __syncthreads();

    int idx = s_count - 1;
    idx = max(0, min(L - 1, idx));   // matches JAX clip-mode gather

    // ---- prefetch this wave's action ids in parallel (kills the serial chain)
    const int kw = chunk * KPB + wave * KPW;           // wave's first output
    const int* ak = action_keys + b * K;
    int av = 0;
    if (lane < KPW) av = actions[ak[kw + lane]];

    // ---- enc_last fragment: lane gl holds floats {gl*4 + j*64 .. +3}, j=0..3
    const float* encrow = &encoded[((size_t)(b * L + idx)) * H];
    const float4 e0 = *(const float4*)&encrow[gl * 4];
    const float4 e1 = *(const float4*)&encrow[gl * 4 + 64];
    const float4 e2 = *(const float4*)&encrow[gl * 4 + 128];
    const float4 e3 = *(const float4*)&encrow[gl * 4 + 192];

    // ---- each 16-lane group computes KPG outputs; 2 at a time for MLP ----
    #pragma unroll
    for (int i = 0; i < KPG; i += 2) {
        const int o0 = gid * KPG + i;         // wave-local output indices
        const int o1 = o0 + 1;
        const int a0 = __shfl(av, o0, 64);
        const int a1 = __shfl(av, o1, 64);

        const float* r0 = &rel_emb[(size_t)a0 * H];
        const float* r1 = &rel_emb[(size_t)a1 * H];

        float4 r00 = *(const float4*)&r0[gl * 4];
        float4 r01 = *(const float4*)&r0[gl * 4 + 64];
        float4 r02 = *(const float4*)&r0[gl * 4 + 128];
        float4 r03 = *(const float4*)&r0[gl * 4 + 192];
        float4 r10 = *(const float4*)&r1[gl * 4];
        float4 r11 = *(const float4*)&r1[gl * 4 + 64];
        float4 r12 = *(const float4*)&r1[gl * 4 + 128];
        float4 r13 = *(const float4*)&r1[gl * 4 + 192];

        float p0 = r00.x * e0.x + r00.y * e0.y + r00.z * e0.z + r00.w * e0.w;
        p0 += r01.x * e1.x + r01.y * e1.y + r01.z * e1.z + r01.w * e1.w;
        p0 += r02.x * e2.x + r02.y * e2.y + r02.z * e2.z + r02.w * e2.w;
        p0 += r03.x * e3.x + r03.y * e3.y + r03.z * e3.z + r03.w * e3.w;

        float p1 = r10.x * e0.x + r10.y * e0.y + r10.z * e0.z + r10.w * e0.w;
        p1 += r11.x * e1.x + r11.y * e1.y + r11.z * e1.z + r11.w * e1.w;
        p1 += r12.x * e2.x + r12.y * e2.y + r12.z * e2.z + r12.w * e2.w;
        p1 += r13.x * e3.x + r13.y * e3.y + r13.z * e3.z + r13.w * e3.w;

        // reduce across the 16-lane group (xor masks stay within group)
        #pragma unroll
        for (int off = 1; off < 16; off <<= 1) {
            p0 += __shfl_xor(p0, off, 64);
            p1 += __shfl_xor(p1, off, 64);
        }
        if (gl == 0) {
            out[b * K + kw + o0] = p0;
            out[b * K + kw + o1] = p1;
        }
    }
}

extern "C" void kernel_launch(void* const* d_in, const int* in_sizes, int n_in,
                              void* d_out, int out_size, void* d_ws, size_t ws_size,
                              hipStream_t stream)
{
    const int*   entities    = (const int*)d_in[0];
    // d_in[1] = relations (unused by the reference computation)
    const int*   actions     = (const int*)d_in[2];
    const int*   action_keys = (const int*)d_in[3];
    const float* encoded     = (const float*)d_in[4];
    const float* rel_emb     = (const float*)d_in[5];
    float*       out         = (float*)d_out;

    hipLaunchKernelGGL(preds_fused_kernel,
                       dim3(B * CHUNKS), dim3(THREADS), 0, stream,
                       entities, actions, action_keys, encoded, rel_emb, out);
}